// Round 10
// baseline (88.842 us; speedup 1.0000x reference)
//
#include <hip/hip_runtime.h>

#define NKC 256   // clusters (K)
#define ND  64    // feature dim (D)

using v8bf = __attribute__((ext_vector_type(8))) __bf16;
using v4f  = __attribute__((ext_vector_type(4))) float;
using v4u  = __attribute__((ext_vector_type(4))) unsigned int;

// R10: persistent single-generation grid (512 blocks = 2/CU exactly) +
// software x-prefetch. Each block stages clusters ONCE (4x less staging
// than R9), then loops 4 tiles barrier-free; next tile's x loads are
// issued after the MFMA loop so HBM latency hides under epilogue+stores.
//  - clusters f32->bf16 swizzled LDS via native casts (v_cvt_pk_bf16_f32)
//  - swapped-operand MFMA (D[row=cluster, col=x-row])
//  - wave-private 4KB LDS transpose -> 1KB-contiguous nontemporal stores
__global__ __launch_bounds__(512, 4)
void cluster_kernel(const float* __restrict__ x,
                    const float* __restrict__ clusters,
                    float* __restrict__ out,
                    int ntiles) {
    __shared__ __align__(16) unsigned short sc[NKC * ND];   // 32 KB clusters
    __shared__ float scsq[NKC];                             // 1 KB
    __shared__ __align__(16) float tsc[8 * 1024];           // 32 KB transpose, 4KB/wave

    const int t    = threadIdx.x;
    const int lane = t & 63;
    const int wid  = t >> 6;        // wave in block (0..7)
    const int lr   = lane & 15;
    const int hi   = lane >> 4;     // 0..3
    const int kg   = hi << 3;       // k-offset within 32: 0,8,16,24
    const int nblk = gridDim.x;

    // ---- prologue: issue first tile's x loads (hide under staging)
    int tile = blockIdx.x;
    const float* xp0 = x + ((size_t)(tile * 128 + wid * 16 + lr)) * ND + kg;
    v4f nx00 = *(const v4f*)(xp0);
    v4f nx01 = *(const v4f*)(xp0 + 4);
    v4f nx10 = *(const v4f*)(xp0 + 32);
    v4f nx11 = *(const v4f*)(xp0 + 36);

    // ---- stage clusters ONCE: f32 -> bf16 swizzled LDS + per-row sumsq.
    {
        const int seg  = t & 3;
        const int rloc = t >> 2;            // 0..127
#pragma unroll
        for (int it = 0; it < 2; ++it) {
            const int crow = it * 128 + rloc;
            const float* cp = clusters + crow * ND + seg * 16;
            v4f c0 = *(const v4f*)(cp);
            v4f c1 = *(const v4f*)(cp + 4);
            v4f c2 = *(const v4f*)(cp + 8);
            v4f c3 = *(const v4f*)(cp + 12);
            float cv[16];
            *(v4f*)&cv[0] = c0; *(v4f*)&cv[4] = c1;
            *(v4f*)&cv[8] = c2; *(v4f*)&cv[12] = c3;
            float ss = 0.f;
#pragma unroll
            for (int i = 0; i < 16; ++i) ss += cv[i] * cv[i];
            ss += __shfl_xor(ss, 1);
            ss += __shfl_xor(ss, 2);
            if (seg == 0) scsq[crow] = ss;
            v8bf w0, w1;
#pragma unroll
            for (int i = 0; i < 8; ++i) {
                w0[i] = (__bf16)cv[i];        // -> v_cvt_pk_bf16_f32 pairs
                w1[i] = (__bf16)cv[8 + i];
            }
            const int swz = (crow & 7) << 4;
            const int byte0 = crow * 128 + seg * 32;
            *(v8bf*)((char*)sc + ( byte0       ^ swz)) = w0;
            *(v8bf*)((char*)sc + ((byte0 + 16) ^ swz)) = w1;
        }
    }
    __syncthreads();   // the only barrier in the kernel

    char* slice = (char*)tsc + wid * 4096;
    const int q = lr & 3;                 // row-local within transpose round

    while (tile < ntiles) {
        // consume prefetched x
        v4f x00 = nx00, x01 = nx01, x10 = nx10, x11 = nx11;
        const int next = tile + nblk;

        // ---- convert x (native casts), full-row sumsq
        float v0[8], v1[8];
        *(v4f*)&v0[0] = x00; *(v4f*)&v0[4] = x01;
        *(v4f*)&v1[0] = x10; *(v4f*)&v1[4] = x11;

        float p = 0.f;
#pragma unroll
        for (int i = 0; i < 8; ++i) p += v0[i] * v0[i] + v1[i] * v1[i];
        p += __shfl_xor(p, 16);
        p += __shfl_xor(p, 32);

        v8bf a0, a1;
#pragma unroll
        for (int i = 0; i < 8; ++i) {
            a0[i] = (__bf16)v0[i];   // x fragment (B operand), k 0..31
            a1[i] = (__bf16)v1[i];   // x fragment, k 32..63
        }

        // ---- MFMA: 16 cluster-tiles x (K=64 as 2 steps). A = clusters in LDS.
        v4f acc[16];
#pragma unroll
        for (int j = 0; j < 16; ++j) {
            const int brow = (j << 4) + lr;           // cluster row within tile
            const int bswz = (brow & 7) << 4;
            v8bf c0 = *(v8bf*)((char*)sc + ((brow * 128      + kg * 2) ^ bswz));
            v8bf c1 = *(v8bf*)((char*)sc + ((brow * 128 + 64 + kg * 2) ^ bswz));
            v4f c = {0.f, 0.f, 0.f, 0.f};
            c = __builtin_amdgcn_mfma_f32_16x16x32_bf16(c0, a0, c, 0, 0, 0);
            c = __builtin_amdgcn_mfma_f32_16x16x32_bf16(c1, a1, c, 0, 0, 0);
            acc[j] = c;   // D[row=cluster 16j+4hi+r, col=x-row lr] per lane
        }

        // ---- prefetch next tile's x rows NOW (latency hides under
        // epilogue + transpose + stores; loads precede stores so the
        // next-iteration wait stays a counted vmcnt, not vmcnt(0))
        if (next < ntiles) {
            const float* xq = x + ((size_t)(next * 128 + wid * 16 + lr)) * ND + kg;
            nx00 = *(const v4f*)(xq);
            nx01 = *(const v4f*)(xq + 4);
            nx10 = *(const v4f*)(xq + 32);
            nx11 = *(const v4f*)(xq + 36);
        }

        // ---- epilogue: u = 1/(1+d); normalize fully in registers
        float ps = 0.f;
#pragma unroll
        for (int j = 0; j < 16; ++j) {
            v4f cs = *(const v4f*)&scsq[(j << 4) + (hi << 2)];
#pragma unroll
            for (int r = 0; r < 4; ++r) {
                float d = p + cs[r] - 2.0f * acc[j][r];
                float u = __builtin_amdgcn_rcpf(1.0f + d);
                acc[j][r] = u;
                ps += u;
            }
        }
        ps += __shfl_xor(ps, 16);
        ps += __shfl_xor(ps, 32);
        const float inv = __builtin_amdgcn_rcpf(ps);
#pragma unroll
        for (int j = 0; j < 16; ++j) {
#pragma unroll
            for (int r = 0; r < 4; ++r) acc[j][r] *= inv;
        }

        // ---- wave-private transpose (4KB slice, no block barrier):
        // 4 rounds x 4 rows; canonical byte 64j+16hi stored at 64(j^q)+16hi,
        // reader inverts with j' = (lane>>2)^q2 -> 1KB-contiguous nt stores.
        const int rowbase = tile * 128 + wid * 16;
#pragma unroll
        for (int rnd = 0; rnd < 4; ++rnd) {
            if ((lr >> 2) == rnd) {
#pragma unroll
                for (int j = 0; j < 16; ++j) {
                    *(v4u*)(slice + q * 1024 + (((j ^ q) << 6) + (hi << 4))) =
                        *(v4u*)&acc[j];
                }
            }
            __asm__ volatile("s_waitcnt lgkmcnt(0)" ::: "memory");
#pragma unroll
            for (int q2 = 0; q2 < 4; ++q2) {
                v4u val = *(v4u*)(slice + q2 * 1024 +
                                  ((((lane >> 2) ^ q2) << 6) + ((lane & 3) << 4)));
                float* orow = out + (size_t)(rowbase + rnd * 4 + q2) * NKC;
                __builtin_nontemporal_store(val, (v4u*)(orow + (lane << 2)));
            }
            __asm__ volatile("s_waitcnt lgkmcnt(0)" ::: "memory");  // WAR on slice
        }

        tile = next;
    }
}

extern "C" void kernel_launch(void* const* d_in, const int* in_sizes, int n_in,
                              void* d_out, int out_size, void* d_ws, size_t ws_size,
                              hipStream_t stream) {
    const float* x        = (const float*)d_in[0];
    const float* clusters = (const float*)d_in[1];
    float* out = (float*)d_out;
    const int N = in_sizes[0] / ND;                 // 262144
    const int ntiles = N / 128;                     // 2048

    cluster_kernel<<<512, 512, 0, stream>>>(x, clusters, out, ntiles);
}

// Round 11
// 67.895 us; speedup vs baseline: 1.3085x; 1.3085x over previous
//
#include <hip/hip_runtime.h>

#define NKC 256   // clusters (K)
#define ND  64    // feature dim (D)

using v8bf = __attribute__((ext_vector_type(8))) __bf16;
using v4f  = __attribute__((ext_vector_type(4))) float;
using v4u  = __attribute__((ext_vector_type(4))) unsigned int;

__device__ __forceinline__ void convert_x(v4f x00, v4f x01, v4f x10, v4f x11,
                                          v8bf& a0, v8bf& a1, float& p) {
    float v0[8], v1[8];
    *(v4f*)&v0[0] = x00; *(v4f*)&v0[4] = x01;
    *(v4f*)&v1[0] = x10; *(v4f*)&v1[4] = x11;
    p = 0.f;
#pragma unroll
    for (int i = 0; i < 8; ++i) p += v0[i] * v0[i] + v1[i] * v1[i];
    p += __shfl_xor(p, 16);   // full-row sumsq across the 4 hi-groups
    p += __shfl_xor(p, 32);
#pragma unroll
    for (int i = 0; i < 8; ++i) {
        a0[i] = (__bf16)v0[i];   // -> v_cvt_pk_bf16_f32 pairs
        a1[i] = (__bf16)v1[i];
    }
}

// MFMA + epilogue + wave-private LDS transpose + nt full-line stores for one
// 128-row tile (this wave's 16 rows). Never waits on vmcnt.
__device__ __forceinline__ void tile_compute_store(
    const unsigned short* sc, const float* scsq, char* slice,
    v8bf a0, v8bf a1, float p,
    int lr, int hi, int kg, int lane, int rowbase, float* __restrict__ out) {
    // ---- MFMA: 16 cluster-tiles x (K=64 as 2 steps). A = clusters in LDS.
    v4f acc[16];
#pragma unroll
    for (int j = 0; j < 16; ++j) {
        const int brow = (j << 4) + lr;           // cluster row within tile
        const int bswz = (brow & 7) << 4;
        v8bf c0 = *(v8bf*)((char*)sc + ((brow * 128      + kg * 2) ^ bswz));
        v8bf c1 = *(v8bf*)((char*)sc + ((brow * 128 + 64 + kg * 2) ^ bswz));
        v4f c = {0.f, 0.f, 0.f, 0.f};
        c = __builtin_amdgcn_mfma_f32_16x16x32_bf16(c0, a0, c, 0, 0, 0);
        c = __builtin_amdgcn_mfma_f32_16x16x32_bf16(c1, a1, c, 0, 0, 0);
        acc[j] = c;   // D[row=cluster 16j+4hi+r, col=x-row lr] per lane
    }

    // ---- epilogue: u = 1/(1+d); normalize fully in registers
    float ps = 0.f;
#pragma unroll
    for (int j = 0; j < 16; ++j) {
        v4f cs = *(const v4f*)&scsq[(j << 4) + (hi << 2)];
#pragma unroll
        for (int r = 0; r < 4; ++r) {
            float d = p + cs[r] - 2.0f * acc[j][r];
            float u = __builtin_amdgcn_rcpf(1.0f + d);
            acc[j][r] = u;
            ps += u;
        }
    }
    ps += __shfl_xor(ps, 16);
    ps += __shfl_xor(ps, 32);
    const float inv = __builtin_amdgcn_rcpf(ps);
#pragma unroll
    for (int j = 0; j < 16; ++j) {
#pragma unroll
        for (int r = 0; r < 4; ++r) acc[j][r] *= inv;
    }

    // ---- wave-private transpose (4KB slice, no block barrier):
    // 4 rounds x 4 rows; canonical byte 64j+16hi stored at 64(j^q)+16hi,
    // reader inverts with j' = (lane>>2)^q2 -> 1KB-contiguous nt stores.
    const int q = lr & 3;
#pragma unroll
    for (int rnd = 0; rnd < 4; ++rnd) {
        if ((lr >> 2) == rnd) {
#pragma unroll
            for (int j = 0; j < 16; ++j) {
                *(v4u*)(slice + q * 1024 + (((j ^ q) << 6) + (hi << 4))) =
                    *(v4u*)&acc[j];
            }
        }
        __asm__ volatile("s_waitcnt lgkmcnt(0)" ::: "memory");
#pragma unroll
        for (int q2 = 0; q2 < 4; ++q2) {
            v4u val = *(v4u*)(slice + q2 * 1024 +
                              ((((lane >> 2) ^ q2) << 6) + ((lane & 3) << 4)));
            float* orow = out + (size_t)(rowbase + rnd * 4 + q2) * NKC;
            __builtin_nontemporal_store(val, (v4u*)(orow + (lane << 2)));
        }
        __asm__ volatile("s_waitcnt lgkmcnt(0)" ::: "memory");  // WAR on slice
    }
}

// R11: 1024 blocks x 512 threads, 2 contiguous 128-row tiles per block.
// Clusters staged ONCE per block (2x less staging + 2 generations vs R9).
// Tile-1's x loads are issued after the barrier and CONVERTED BEFORE tile-0's
// stores — the vmcnt wait happens with zero stores outstanding (vmcnt is a
// FIFO counter: consuming a load after a store burst drains the burst — the
// R10 pathology). Tile-1 MFMA runs from LDS/regs while tile-0 stores drain.
__global__ __launch_bounds__(512, 4)
void cluster_kernel(const float* __restrict__ x,
                    const float* __restrict__ clusters,
                    float* __restrict__ out) {
    __shared__ __align__(16) unsigned short sc[NKC * ND];   // 32 KB clusters
    __shared__ float scsq[NKC];                             // 1 KB
    __shared__ __align__(16) float tsc[8 * 1024];           // 32 KB transpose, 4KB/wave

    const int t    = threadIdx.x;
    const int lane = t & 63;
    const int wid  = t >> 6;        // wave in block (0..7)
    const int lr   = lane & 15;
    const int hi   = lane >> 4;     // 0..3
    const int kg   = hi << 3;       // k-offset within 32: 0,8,16,24

    // ---- issue tile-0 x loads FIRST (latency hides under staging)
    const int row0 = blockIdx.x * 256 + wid * 16 + lr;      // tile-0 row
    const float* xp = x + (size_t)row0 * ND + kg;
    v4f x00 = *(const v4f*)(xp);
    v4f x01 = *(const v4f*)(xp + 4);
    v4f x10 = *(const v4f*)(xp + 32);
    v4f x11 = *(const v4f*)(xp + 36);

    // ---- stage clusters ONCE: f32 -> bf16 swizzled LDS + per-row sumsq
    {
        const int seg  = t & 3;
        const int rloc = t >> 2;            // 0..127
#pragma unroll
        for (int it = 0; it < 2; ++it) {
            const int crow = it * 128 + rloc;
            const float* cp = clusters + crow * ND + seg * 16;
            v4f c0 = *(const v4f*)(cp);
            v4f c1 = *(const v4f*)(cp + 4);
            v4f c2 = *(const v4f*)(cp + 8);
            v4f c3 = *(const v4f*)(cp + 12);
            float cv[16];
            *(v4f*)&cv[0] = c0; *(v4f*)&cv[4] = c1;
            *(v4f*)&cv[8] = c2; *(v4f*)&cv[12] = c3;
            float ss = 0.f;
#pragma unroll
            for (int i = 0; i < 16; ++i) ss += cv[i] * cv[i];
            ss += __shfl_xor(ss, 1);
            ss += __shfl_xor(ss, 2);
            if (seg == 0) scsq[crow] = ss;
            v8bf w0, w1;
#pragma unroll
            for (int i = 0; i < 8; ++i) {
                w0[i] = (__bf16)cv[i];
                w1[i] = (__bf16)cv[8 + i];
            }
            const int swz = (crow & 7) << 4;
            const int byte0 = crow * 128 + seg * 32;
            *(v8bf*)((char*)sc + ( byte0       ^ swz)) = w0;
            *(v8bf*)((char*)sc + ((byte0 + 16) ^ swz)) = w1;
        }
    }
    __syncthreads();   // the only barrier in the kernel

    // ---- issue tile-1 x loads now; consumed before any store is issued
    const float* xq = x + (size_t)(row0 + 128) * ND + kg;
    v4f y00 = *(const v4f*)(xq);
    v4f y01 = *(const v4f*)(xq + 4);
    v4f y10 = *(const v4f*)(xq + 32);
    v4f y11 = *(const v4f*)(xq + 36);

    char* slice = (char*)tsc + wid * 4096;

    // ---- tile 0: convert (waits only on its own 4 loads) + compute
    v8bf a0, a1; float p;
    convert_x(x00, x01, x10, x11, a0, a1, p);

    // tile-1 convert BEFORE tile-0 stores: only 4 loads outstanding -> counted
    // wait; after this, no vmcnt wait exists anywhere in the kernel.
    v8bf b0, b1; float pb;
    convert_x(y00, y01, y10, y11, b0, b1, pb);

    tile_compute_store(sc, scsq, slice, a0, a1, p,
                       lr, hi, kg, lane, blockIdx.x * 256 + wid * 16, out);

    // ---- tile 1: pure LDS/reg compute while tile-0 stores drain
    tile_compute_store(sc, scsq, slice, b0, b1, pb,
                       lr, hi, kg, lane, blockIdx.x * 256 + 128 + wid * 16, out);
}

extern "C" void kernel_launch(void* const* d_in, const int* in_sizes, int n_in,
                              void* d_out, int out_size, void* d_ws, size_t ws_size,
                              hipStream_t stream) {
    const float* x        = (const float*)d_in[0];
    const float* clusters = (const float*)d_in[1];
    float* out = (float*)d_out;
    const int N = in_sizes[0] / ND;                 // 262144

    cluster_kernel<<<N / 256, 512, 0, stream>>>(x, clusters, out);
}

// Round 12
// 58.124 us; speedup vs baseline: 1.5285x; 1.1681x over previous
//
#include <hip/hip_runtime.h>

#define NKC 256   // clusters (K)
#define ND  64    // feature dim (D)

using v8bf = __attribute__((ext_vector_type(8))) __bf16;
using v4f  = __attribute__((ext_vector_type(4))) float;
using v4u  = __attribute__((ext_vector_type(4))) unsigned int;

// R12 = R9 (best: 58.3us), reverted after R10/R11 multi-tile variants both
// spilled (holding next-tile x/fragments live across the acc[16]=64-reg
// region exceeds the 128-VGPR/(512,4) cap -> scratch traffic in hot path).
// Structure:
//  - 512-thread blocks, one 128-row tile each; grid 2048 (4 generations)
//  - x loads issued FIRST (cached — nt x-loads re-fetch sectors 4x, R7)
//  - clusters f32->bf16 swizzled into LDS via native casts (v_cvt_pk path)
//    + per-row sumsq; ONE barrier total
//  - swapped-operand MFMA: D[row=cluster, col=x-row] -> lane owns one x-row,
//    scalar row-sum, no broadcast epilogue
//  - wave-private 4KB LDS transpose (no 2nd barrier) -> each store writes a
//    full 1KB output row contiguously (64B half-line stores cost ~185MB of
//    L2 write-allocate RMW fetch, R3); nontemporal (output never re-read)
__global__ __launch_bounds__(512, 4)
void cluster_kernel(const float* __restrict__ x,
                    const float* __restrict__ clusters,
                    float* __restrict__ out) {
    __shared__ __align__(16) unsigned short sc[NKC * ND];   // 32 KB clusters
    __shared__ float scsq[NKC];                             // 1 KB
    __shared__ __align__(16) float tsc[8 * 1024];           // 32 KB transpose, 4KB/wave

    const int t    = threadIdx.x;
    const int lane = t & 63;
    const int wid  = t >> 6;        // wave in block (0..7)
    const int lr   = lane & 15;
    const int hi   = lane >> 4;     // 0..3
    const int kg   = hi << 3;       // k-offset within 32: 0,8,16,24

    // ---- issue this lane's x-row loads FIRST (HBM latency hides under staging)
    const int row = blockIdx.x * 128 + wid * 16 + lr;
    const float* xp = x + (size_t)row * ND + kg;
    v4f x00 = *(const v4f*)(xp);
    v4f x01 = *(const v4f*)(xp + 4);
    v4f x10 = *(const v4f*)(xp + 32);
    v4f x11 = *(const v4f*)(xp + 36);

    // ---- stage clusters: f32 -> bf16 swizzled LDS + per-row sumsq.
    {
        const int seg  = t & 3;
        const int rloc = t >> 2;            // 0..127
#pragma unroll
        for (int it = 0; it < 2; ++it) {
            const int crow = it * 128 + rloc;
            const float* cp = clusters + crow * ND + seg * 16;
            v4f c0 = *(const v4f*)(cp);
            v4f c1 = *(const v4f*)(cp + 4);
            v4f c2 = *(const v4f*)(cp + 8);
            v4f c3 = *(const v4f*)(cp + 12);
            float cv[16];
            *(v4f*)&cv[0] = c0; *(v4f*)&cv[4] = c1;
            *(v4f*)&cv[8] = c2; *(v4f*)&cv[12] = c3;
            float ss = 0.f;
#pragma unroll
            for (int i = 0; i < 16; ++i) ss += cv[i] * cv[i];
            ss += __shfl_xor(ss, 1);
            ss += __shfl_xor(ss, 2);
            if (seg == 0) scsq[crow] = ss;
            v8bf w0, w1;
#pragma unroll
            for (int i = 0; i < 8; ++i) {
                w0[i] = (__bf16)cv[i];        // -> v_cvt_pk_bf16_f32 pairs
                w1[i] = (__bf16)cv[8 + i];
            }
            const int swz = (crow & 7) << 4;
            const int byte0 = crow * 128 + seg * 32;
            *(v8bf*)((char*)sc + ( byte0       ^ swz)) = w0;
            *(v8bf*)((char*)sc + ((byte0 + 16) ^ swz)) = w1;
        }
    }
    __syncthreads();   // the only barrier in the kernel

    // ---- convert x (native casts), full-row sumsq
    float v0[8], v1[8];
    *(v4f*)&v0[0] = x00; *(v4f*)&v0[4] = x01;
    *(v4f*)&v1[0] = x10; *(v4f*)&v1[4] = x11;

    float p = 0.f;
#pragma unroll
    for (int i = 0; i < 8; ++i) p += v0[i] * v0[i] + v1[i] * v1[i];
    p += __shfl_xor(p, 16);
    p += __shfl_xor(p, 32);

    v8bf a0, a1;
#pragma unroll
    for (int i = 0; i < 8; ++i) {
        a0[i] = (__bf16)v0[i];   // x fragment (B operand), k 0..31
        a1[i] = (__bf16)v1[i];   // x fragment, k 32..63
    }

    // ---- MFMA: 16 cluster-tiles x (K=64 as 2 steps). A = clusters from LDS.
    v4f acc[16];
#pragma unroll
    for (int j = 0; j < 16; ++j) {
        const int brow = (j << 4) + lr;           // cluster row within tile
        const int bswz = (brow & 7) << 4;
        v8bf c0 = *(v8bf*)((char*)sc + ((brow * 128      + kg * 2) ^ bswz));
        v8bf c1 = *(v8bf*)((char*)sc + ((brow * 128 + 64 + kg * 2) ^ bswz));
        v4f c = {0.f, 0.f, 0.f, 0.f};
        c = __builtin_amdgcn_mfma_f32_16x16x32_bf16(c0, a0, c, 0, 0, 0);
        c = __builtin_amdgcn_mfma_f32_16x16x32_bf16(c1, a1, c, 0, 0, 0);
        acc[j] = c;   // D[row=cluster 16j+4hi+r, col=x-row lr] per lane
    }

    // ---- epilogue: u = 1/(1+d); normalize fully in registers
    float ps = 0.f;
#pragma unroll
    for (int j = 0; j < 16; ++j) {
        v4f cs = *(const v4f*)&scsq[(j << 4) + (hi << 2)];
#pragma unroll
        for (int r = 0; r < 4; ++r) {
            float d = p + cs[r] - 2.0f * acc[j][r];
            float u = __builtin_amdgcn_rcpf(1.0f + d);
            acc[j][r] = u;
            ps += u;
        }
    }
    ps += __shfl_xor(ps, 16);
    ps += __shfl_xor(ps, 32);
    const float inv = __builtin_amdgcn_rcpf(ps);
#pragma unroll
    for (int j = 0; j < 16; ++j) {
#pragma unroll
        for (int r = 0; r < 4; ++r) acc[j][r] *= inv;
    }

    // ---- wave-private transpose (4KB slice, NO block barrier):
    // 4 rounds x 4 rows. Writer lane (lr=4*rnd+q, hi) places acc[j] at
    // q*1024 + 64*(j^q) + 16*hi (write 2-way bank alias = free, read even).
    // Reader inverts with j' = (lane>>2)^q2 -> 1KB-contiguous nt row stores.
    char* slice = (char*)tsc + wid * 4096;
    const int q = lr & 3;                 // row-local within round
    const int rowbase = blockIdx.x * 128 + wid * 16;
#pragma unroll
    for (int rnd = 0; rnd < 4; ++rnd) {
        if ((lr >> 2) == rnd) {
#pragma unroll
            for (int j = 0; j < 16; ++j) {
                *(v4u*)(slice + q * 1024 + (((j ^ q) << 6) + (hi << 4))) =
                    *(v4u*)&acc[j];
            }
        }
        __asm__ volatile("s_waitcnt lgkmcnt(0)" ::: "memory");
#pragma unroll
        for (int q2 = 0; q2 < 4; ++q2) {
            v4u val = *(v4u*)(slice + q2 * 1024 +
                              ((((lane >> 2) ^ q2) << 6) + ((lane & 3) << 4)));
            float* orow = out + (size_t)(rowbase + rnd * 4 + q2) * NKC;
            __builtin_nontemporal_store(val, (v4u*)(orow + (lane << 2)));
        }
        __asm__ volatile("s_waitcnt lgkmcnt(0)" ::: "memory");  // WAR on slice
    }
}

extern "C" void kernel_launch(void* const* d_in, const int* in_sizes, int n_in,
                              void* d_out, int out_size, void* d_ws, size_t ws_size,
                              hipStream_t stream) {
    const float* x        = (const float*)d_in[0];
    const float* clusters = (const float*)d_in[1];
    float* out = (float*)d_out;
    const int N = in_sizes[0] / ND;                 // 262144

    cluster_kernel<<<N / 128, 512, 0, stream>>>(x, clusters, out);
}